// Round 19
// baseline (453.095 us; speedup 1.0000x reference)
//
#include <hip/hip_runtime.h>
#include <hip/hip_bf16.h>

// Device buffers are FLOAT32 (confirmed R4/R5). bf16 MFMA compute, f32 accum.
// R18->R19: Q/KV projections fused into ONE GEMM over concatenated weights
// [wq;wk;wv] (2048x6144x4096, 768 blocks = 3/CU) with the R16-proven fused
// RoPE epilogue (shfl_xor pair exchange): Q->q_bf, K->cache_k+k_bf, V->cache_v.
// Deletes both combine kernels + 100MB partial traffic + one dispatch.
// O-proj/attn unchanged (R18-proven). Toolchain rules: no 512-thr blocks
// (VGPR cap 128, R13/R14); no min-waves launch_bounds arg (R11).

typedef __attribute__((ext_vector_type(8))) short short8_t;
typedef __attribute__((ext_vector_type(2))) unsigned uint2_t;
typedef __attribute__((ext_vector_type(8))) __bf16 bf16x8;
typedef __attribute__((ext_vector_type(4))) float f32x4;
typedef __attribute__((ext_vector_type(16))) float f32x16;

#define SEQLEN 2048
#define QSCALE 0.08838834764831845f   // HEAD_DIM^-0.5, folded into Q epilogue

__device__ __forceinline__ short f2b(float f) {
  if (!__builtin_isfinite(f)) f = 0.0f;   // diagnostic scrub (final stores only)
  union { float f; unsigned u; } v; v.f = f;
  unsigned r = (v.u + 0x7fffu + ((v.u >> 16) & 1u)) >> 16;  // RNE
  return (short)r;
}
__device__ __forceinline__ float sf(float f) {
  return __builtin_isfinite(f) ? f : 0.0f;
}
__device__ __forceinline__ short8_t cvt8(const float* p) {
  f32x4 a = *(const f32x4*)p;
  f32x4 b = *(const f32x4*)(p + 4);
  short8_t o;
  o[0] = f2b(a[0]); o[1] = f2b(a[1]); o[2] = f2b(a[2]); o[3] = f2b(a[3]);
  o[4] = f2b(b[0]); o[5] = f2b(b[1]); o[6] = f2b(b[2]); o[7] = f2b(b[3]);
  return o;
}
// pack two f32 -> (bf16 hi<<16 | bf16 lo); inputs finite by construction
__device__ __forceinline__ unsigned pkb(float lo, float hi) {
  union { float f; unsigned u; } a, b; a.f = lo; b.f = hi;
  unsigned ra = (a.u + 0x7fffu + ((a.u >> 16) & 1u)) >> 16;
  unsigned rb = (b.u + 0x7fffu + ((b.u >> 16) & 1u)) & 0xffff0000u;
  return rb | ra;
}

#define GLD16(gp, lp) __builtin_amdgcn_global_load_lds( \
    (const __attribute__((address_space(1))) void*)(gp), \
    (__attribute__((address_space(3))) void*)(lp), 16, 0, 0)

// ---------------------------------------------------------------------------
__global__ __launch_bounds__(256) void cvt_bf16(
    const float* __restrict__ in, short* __restrict__ out)
{
  size_t i = ((size_t)blockIdx.x * 256 + threadIdx.x) * 8;
  *(short8_t*)&out[i] = cvt8(in + i);
}

// ---------------------------------------------------------------------------
// Plain GEMM (m97 structure): C[m][n] = sum_k A[m][k]*W[n][k]; C f32.
// ---------------------------------------------------------------------------
__global__ __launch_bounds__(256) void gemm_bf(
    const short* __restrict__ A, const short* __restrict__ W,
    float* __restrict__ C, int K, int ldc)
{
  __shared__ short As[128 * 64];
  __shared__ short Ws[128 * 64];
  const int tid  = threadIdx.x;
  const int lane = tid & 63;
  const int wid  = tid >> 6;
  const int l15  = lane & 15;
  const int l4   = lane >> 4;

  const int nwg = (int)(gridDim.x * gridDim.y);
  int bid = (int)(blockIdx.y * gridDim.x + blockIdx.x);
  int swz = (bid & 7) * (nwg >> 3) + (bid >> 3);
  const int m0 = (swz / (int)gridDim.x) * 128;
  const int n0 = (swz % (int)gridDim.x) * 128;

  const int wr = (wid >> 1) * 64;
  const int wc = (wid & 1) * 64;
  const int srow = tid >> 3;
  const int scol = (tid & 7) * 8;

  f32x4 acc[4][4] = {};

  const short* Ab = A + (size_t)(m0 + srow) * K + scol;
  const short* Wb = W + (size_t)(n0 + srow) * K + scol;

  for (int k0 = 0; k0 < K; k0 += 64) {
#pragma unroll
    for (int i = 0; i < 4; ++i) {
      GLD16(Ab + (size_t)(i * 32) * K + k0, &As[(i * 32 + wid * 8) * 64]);
      GLD16(Wb + (size_t)(i * 32) * K + k0, &Ws[(i * 32 + wid * 8) * 64]);
    }
    __syncthreads();

#pragma unroll
    for (int kk = 0; kk < 2; ++kk) {
      bf16x8 af[4], wf[4];
#pragma unroll
      for (int m = 0; m < 4; ++m)
        af[m] = *(const bf16x8*)&As[(wr + m * 16 + l15) * 64 + kk * 32 + l4 * 8];
#pragma unroll
      for (int n = 0; n < 4; ++n)
        wf[n] = *(const bf16x8*)&Ws[(wc + n * 16 + l15) * 64 + kk * 32 + l4 * 8];
#pragma unroll
      for (int m = 0; m < 4; ++m)
#pragma unroll
        for (int n = 0; n < 4; ++n)
          acc[m][n] = __builtin_amdgcn_mfma_f32_16x16x32_bf16(af[m], wf[n], acc[m][n], 0, 0, 0);
    }
    __syncthreads();
  }

#pragma unroll
  for (int m = 0; m < 4; ++m) {
    int rbase = m0 + wr + m * 16 + l4 * 4;
#pragma unroll
    for (int n = 0; n < 4; ++n) {
      int cbase = n0 + wc + n * 16 + l15;
#pragma unroll
      for (int r = 0; r < 4; ++r)
        C[(size_t)(rbase + r) * ldc + cbase] = sf(acc[m][n][r]);
    }
  }
}

// ---------------------------------------------------------------------------
// Fused QKV GEMM: A = x_bf [2048][4096], W = [wq;wk;wv] bf16 [6144][4096].
// Epilogue (R16-proven rope-by-shfl): cols 0..4095  -> q_bf = rope*QSCALE bf16
//                                     cols 4096..5119 -> cache_k f32 + k_bf (roped)
//                                     cols 5120..6143 -> cache_v f32 (plain)
// ---------------------------------------------------------------------------
__global__ __launch_bounds__(256) void gemm_qkv(
    const short* __restrict__ A, const short* __restrict__ W,
    short* __restrict__ qb, float* __restrict__ ck, short* __restrict__ kb,
    float* __restrict__ cv,
    const float* __restrict__ fc, const float* __restrict__ fs)
{
  __shared__ short As[128 * 64];
  __shared__ short Ws[128 * 64];
  const int K = 4096;
  const int tid  = threadIdx.x;
  const int lane = tid & 63;
  const int wid  = tid >> 6;
  const int l15  = lane & 15;
  const int l4   = lane >> 4;

  const int nwg = (int)(gridDim.x * gridDim.y);   // 768, %8==0
  int bid = (int)(blockIdx.y * gridDim.x + blockIdx.x);
  int swz = (bid & 7) * (nwg >> 3) + (bid >> 3);
  const int m0 = (swz / (int)gridDim.x) * 128;
  const int n0 = (swz % (int)gridDim.x) * 128;

  const int wr = (wid >> 1) * 64;
  const int wc = (wid & 1) * 64;
  const int srow = tid >> 3;
  const int scol = (tid & 7) * 8;

  f32x4 acc[4][4] = {};

  const short* Ab = A + (size_t)(m0 + srow) * K + scol;
  const short* Wb = W + (size_t)(n0 + srow) * K + scol;

  for (int k0 = 0; k0 < K; k0 += 64) {
#pragma unroll
    for (int i = 0; i < 4; ++i) {
      GLD16(Ab + (size_t)(i * 32) * K + k0, &As[(i * 32 + wid * 8) * 64]);
      GLD16(Wb + (size_t)(i * 32) * K + k0, &Ws[(i * 32 + wid * 8) * 64]);
    }
    __syncthreads();

#pragma unroll
    for (int kk = 0; kk < 2; ++kk) {
      bf16x8 af[4], wf[4];
#pragma unroll
      for (int m = 0; m < 4; ++m)
        af[m] = *(const bf16x8*)&As[(wr + m * 16 + l15) * 64 + kk * 32 + l4 * 8];
#pragma unroll
      for (int n = 0; n < 4; ++n)
        wf[n] = *(const bf16x8*)&Ws[(wc + n * 16 + l15) * 64 + kk * 32 + l4 * 8];
#pragma unroll
      for (int m = 0; m < 4; ++m)
#pragma unroll
        for (int n = 0; n < 4; ++n)
          acc[m][n] = __builtin_amdgcn_mfma_f32_16x16x32_bf16(af[m], wf[n], acc[m][n], 0, 0, 0);
    }
    __syncthreads();
  }

  // epilogue: row = m0+wr+m*16+l4*4+r, col = n0+wc+n*16+l15.
  // rope pair (col, col^1) lives in lanes (l15, l15^1) -> shfl_xor(1).
#pragma unroll
  for (int m = 0; m < 4; ++m) {
    int rbase = m0 + wr + m * 16 + l4 * 4;
#pragma unroll
    for (int n = 0; n < 4; ++n) {
      int cbase = n0 + wc + n * 16 + l15;
#pragma unroll
      for (int r = 0; r < 4; ++r) {
        float x = acc[m][n][r];
        float xp = __shfl_xor(x, 1, 64);
        int row = rbase + r;
        int p = (cbase & 127) >> 1;
        float c = fc[row * 64 + p], s = fs[row * 64 + p];
        float o = (l15 & 1) ? (xp * s + x * c) : (x * c - xp * s);
        if (cbase < 4096) {
          qb[(size_t)row * 4096 + cbase] = f2b(o * QSCALE);
        } else if (cbase < 5120) {
          int kc = cbase - 4096;
          ck[(size_t)row * 1024 + kc] = sf(o);
          kb[(size_t)row * 1024 + kc] = f2b(o);
        } else {
          cv[(size_t)row * 1024 + (cbase - 5120)] = sf(x);
        }
      }
    }
  }
}

// cache_v f32 [2048][8*128] -> Vt bf16 [8][128][2048]
__global__ __launch_bounds__(256) void transpose_v(
    const float* __restrict__ cv, short* __restrict__ Vt)
{
  __shared__ short tile[64][72];
  const int t0 = blockIdx.x * 64;
  const int d0 = blockIdx.y * 64;
  const int h  = blockIdx.z;
  const int tid = threadIdx.x;
  const int r = tid >> 3;
  const int c = (tid & 7) * 8;
#pragma unroll
  for (int it = 0; it < 2; ++it) {
    short8_t v = cvt8(&cv[(size_t)(t0 + it * 32 + r) * 1024 + h * 128 + d0 + c]);
    *(short8_t*)&tile[it * 32 + r][c] = v;
  }
  __syncthreads();
#pragma unroll
  for (int it = 0; it < 2; ++it) {
    int dr = it * 32 + r;
    short8_t v;
#pragma unroll
    for (int i = 0; i < 8; ++i) v[i] = tile[c + i][dr];
    *(short8_t*)&Vt[(size_t)(h * 128 + d0 + dr) * SEQLEN + t0 + c] = v;
  }
}

// ---------------------------------------------------------------------------
// Causal flash attention (R15/R18-proven attn_fwd7, unchanged).
// ---------------------------------------------------------------------------
__global__ __launch_bounds__(256) void attn_fwd7(
    const short* __restrict__ Q,    // [2048][4096] bf16, pre-scaled
    const short* __restrict__ Kc,   // [2048][1024] bf16
    const short* __restrict__ Vt,   // [8][128][2048] bf16
    short* __restrict__ O)          // [2048][4096] bf16
{
  const int bid = (int)blockIdx.x;
  const int kvh = bid & 7;
  const int qt  = 63 - (bid >> 3);
  const int tid = (int)threadIdx.x;
  const int wid = tid >> 6;
  const int h   = kvh * 4 + wid;
  const int lane = tid & 63;
  const int l31 = lane & 31;
  const int hi  = lane >> 5;

  __shared__ short Ks[64 * 128];
  __shared__ short Vs[128 * 64];
  __shared__ short P[4][32][72];
  __shared__ float exch[4][32];

  const int q0 = qt * 32;
  const int qg = q0 + l31;
  const int kend = q0 + 32;

  bf16x8 qf[8];
  {
    const short* qp = Q + (size_t)qg * 4096 + h * 128 + hi * 8;
#pragma unroll
    for (int ks = 0; ks < 8; ++ks) qf[ks] = *(const bf16x8*)(qp + ks * 16);
  }

  f32x16 o0 = {}, o1 = {}, o2 = {}, o3 = {};
  float m = -1e30f, l = 0.f;

  const int krow_base = wid * 16;
  const int vrow_base = wid * 32;
  const int xk = l31 & 15;
  const int xv = l31 & 7;

  for (int kt = 0; kt < kend; kt += 64) {
#pragma unroll
    for (int it = 0; it < 4; ++it) {
      int krow = krow_base + it * 4 + (lane >> 4);
      int kch  = (lane & 15) ^ (krow & 15);
      GLD16(Kc + (size_t)(kt + krow) * 1024 + kvh * 128 + kch * 8,
            &Ks[wid * 2048 + it * 512]);
      int vrow = vrow_base + it * 8 + (lane >> 3);
      int vch  = (lane & 7) ^ (vrow & 7);
      GLD16(Vt + (size_t)(kvh * 128 + vrow) * SEQLEN + kt + vch * 8,
            &Vs[wid * 2048 + it * 512]);
    }
    __syncthreads();

    f32x16 s0 = {}, s1 = {};
    {
      __builtin_amdgcn_s_setprio(1);
#pragma unroll
      for (int ks = 0; ks < 8; ++ks) {
        int ch = (ks * 2 + hi) ^ xk;
        bf16x8 k0 = *(const bf16x8*)&Ks[l31 * 128 + ch * 8];
        bf16x8 k1 = *(const bf16x8*)&Ks[(32 + l31) * 128 + ch * 8];
        s0 = __builtin_amdgcn_mfma_f32_32x32x16_bf16(k0, qf[ks], s0, 0, 0, 0);
        s1 = __builtin_amdgcn_mfma_f32_32x32x16_bf16(k1, qf[ks], s1, 0, 0, 0);
      }
      __builtin_amdgcn_s_setprio(0);
    }

    if (kt + 63 > q0) {
#pragma unroll
      for (int r = 0; r < 16; ++r) {
        int crow = (r & 3) + 8 * (r >> 2) + 4 * hi;
        if (kt + crow > qg)      s0[r] = -1e30f;
        if (kt + 32 + crow > qg) s1[r] = -1e30f;
      }
    }
    {
      float t[8];
#pragma unroll
      for (int r = 0; r < 8; ++r)
        t[r] = fmaxf(fmaxf(s0[r], s0[r + 8]), fmaxf(s1[r], s1[r + 8]));
      float pmax = fmaxf(fmaxf(fmaxf(t[0], t[1]), fmaxf(t[2], t[3])),
                         fmaxf(fmaxf(t[4], t[5]), fmaxf(t[6], t[7])));
      pmax = fmaxf(pmax, __shfl_xor(pmax, 32, 64));
      if (!__all(pmax <= m + 8.f)) {
        float mnew = fmaxf(m, pmax);
        float resc = __expf(m - mnew);
        m = mnew; l *= resc;
        if (lane < 32) exch[wid][l31] = resc;
#pragma unroll
        for (int r = 0; r < 16; ++r) {
          float rs = exch[wid][(r & 3) + 8 * (r >> 2) + 4 * hi];
          o0[r] *= rs; o1[r] *= rs; o2[r] *= rs; o3[r] *= rs;
        }
      }
      float psum = 0.f;
#pragma unroll
      for (int r = 0; r < 16; ++r) { s0[r] = __expf(s0[r] - m); psum += s0[r]; }
#pragma unroll
      for (int r = 0; r < 16; ++r) { s1[r] = __expf(s1[r] - m); psum += s1[r]; }
      l += psum + __shfl_xor(psum, 32, 64);
#pragma unroll
      for (int t4 = 0; t4 < 4; ++t4) {
        int c = 8 * t4 + 4 * hi;
        *(uint2_t*)&P[wid][l31][c]      = uint2_t{pkb(s0[4*t4], s0[4*t4+1]), pkb(s0[4*t4+2], s0[4*t4+3])};
        *(uint2_t*)&P[wid][l31][32 + c] = uint2_t{pkb(s1[4*t4], s1[4*t4+1]), pkb(s1[4*t4+2], s1[4*t4+3])};
      }
    }

#pragma unroll
    for (int g = 0; g < 4; ++g) {
      int ch = (g * 2 + hi) ^ xv;
      bf16x8 vf0 = *(const bf16x8*)&Vs[(l31)      * 64 + ch * 8];
      bf16x8 vf1 = *(const bf16x8*)&Vs[(32 + l31) * 64 + ch * 8];
      bf16x8 vf2 = *(const bf16x8*)&Vs[(64 + l31) * 64 + ch * 8];
      bf16x8 vf3 = *(const bf16x8*)&Vs[(96 + l31) * 64 + ch * 8];
      bf16x8 pf  = *(const bf16x8*)&P[wid][l31][g * 16 + hi * 8];
      __builtin_amdgcn_s_setprio(1);
      o0 = __builtin_amdgcn_mfma_f32_32x32x16_bf16(pf, vf0, o0, 0, 0, 0);
      o1 = __builtin_amdgcn_mfma_f32_32x32x16_bf16(pf, vf1, o1, 0, 0, 0);
      o2 = __builtin_amdgcn_mfma_f32_32x32x16_bf16(pf, vf2, o2, 0, 0, 0);
      o3 = __builtin_amdgcn_mfma_f32_32x32x16_bf16(pf, vf3, o3, 0, 0, 0);
      __builtin_amdgcn_s_setprio(0);
    }
    __syncthreads();
  }

  if (lane < 32) exch[wid][l31] = 1.f / l;
#pragma unroll
  for (int r = 0; r < 16; ++r) {
    int crow = (r & 3) + 8 * (r >> 2) + 4 * hi;
    float inv = exch[wid][crow];
    short* ob = O + (size_t)(q0 + crow) * 4096 + h * 128 + l31;
    ob[0]  = f2b(o0[r] * inv);
    ob[32] = f2b(o1[r] * inv);
    ob[64] = f2b(o2[r] * inv);
    ob[96] = f2b(o3[r] * inv);
  }
}

// ---------------------------------------------------------------------------
extern "C" void kernel_launch(void* const* d_in, const int* in_sizes, int n_in,
                              void* d_out, int out_size, void* d_ws, size_t ws_size,
                              hipStream_t stream) {
  const float* x  = (const float*)d_in[0];
  const float* wq = (const float*)d_in[1];
  const float* wk = (const float*)d_in[2];
  const float* wv = (const float*)d_in[3];
  const float* wo = (const float*)d_in[4];
  const float* fc = (const float*)d_in[5];
  const float* fs = (const float*)d_in[6];

  float* out = (float*)d_out;
  float* out_main = out;                               // [2048][4096] f32 (33.5MB)
  float* cache_k  = out + (size_t)2048 * 4096;         // [4096][1024] f32 (16.8MB)
  float* cache_v  = cache_k + (size_t)4096 * 1024;     // [4096][1024] f32 (16.8MB)

  // ws layout (54.5MB, time-multiplexed):
  //   phase A (QKV GEMM): Wcat [0..50.3M) + k_bf [50.3..54.5M)
  //   phase B (attn):     Vt [0..4.2M) + attn_out [4.2..21M) + k_bf [50.3..54.5M)
  //   phase C (O-proj):   attn_out [4.2..21M) + wo_bf [21..54.5M)
  short* Wcat  = (short*)d_ws;                                   // 6144x4096 bf16
  short* k_bf  = (short*)((char*)d_ws + 50331648);               // 4.2MB
  short* Vt    = (short*)d_ws;                                   // 4.2MB (Wcat dead)
  short* attn_out = (short*)((char*)d_ws + 4194304);             // 16.8MB
  short* wo_bf = (short*)((char*)d_ws + 20971520);               // 33.5MB

  // x_bf and q_bf live in out_main (dead until final O-proj):
  short* x_bf = (short*)out_main;                                // 16.8MB
  short* q_bf = x_bf + (size_t)2048 * 4096;                      // 16.8MB

  // 1) converts: x -> x_bf; wq/wk/wv -> Wcat rows 0..6143
  cvt_bf16<<<4096, 256, 0, stream>>>(x, x_bf);
  cvt_bf16<<<8192, 256, 0, stream>>>(wq, Wcat);
  cvt_bf16<<<2048, 256, 0, stream>>>(wk, Wcat + (size_t)4096 * 4096);
  cvt_bf16<<<2048, 256, 0, stream>>>(wv, Wcat + (size_t)5120 * 4096);

  // 2) fused QKV projection (rope in epilogue) -> q_bf, cache_k+k_bf, cache_v
  gemm_qkv<<<dim3(48, 16), 256, 0, stream>>>(x_bf, Wcat, q_bf, cache_k, k_bf,
                                             cache_v, fc, fs);

  // 3) V transpose + cache tail zeros (rows 2048..4095 stay zero)
  transpose_v<<<dim3(32, 2, 8), 256, 0, stream>>>(cache_v, Vt);
  hipMemsetAsync(cache_k + (size_t)2048 * 1024, 0, (size_t)2048 * 1024 * 4, stream);
  hipMemsetAsync(cache_v + (size_t)2048 * 1024, 0, (size_t)2048 * 1024 * 4, stream);

  // 4) attention: 512 single-q-tile blocks, heavy-first, XCD-pinned
  attn_fwd7<<<512, 256, 0, stream>>>(q_bf, k_bf, Vt, attn_out);

  // 5) output projection -> out_main (overwrites x_bf/q_bf; attn done)
  cvt_bf16<<<8192, 256, 0, stream>>>(wo, wo_bf);
  gemm_bf<<<dim3(32, 16), 256, 0, stream>>>(attn_out, wo_bf, out_main, 4096, 4096);
}

// Round 20
// 421.633 us; speedup vs baseline: 1.0746x; 1.0746x over previous
//
#include <hip/hip_runtime.h>
#include <hip/hip_bf16.h>

// Device buffers are FLOAT32 (confirmed R4/R5). bf16 MFMA compute, f32 accum.
// R19->R20: REVERT to R18 verbatim (measured best, 423.2us). R19's fused QKV
// GEMM regressed (224us, FETCH 373MB: L2 locality destroyed by wide-N grid).
// Final ledger at M=2048: split-K ~0, dbuf ~0, atomics -30us, fused-epi -26us,
// fused-QKV -30us; m97 128^2 GEMM structure is the plateau for 256-thr blocks.
// Toolchain rules: 512-thr blocks hard-cap VGPR at 128 (R13/R14); never pass
// a min-waves arg to launch_bounds on ~250-VGPR bodies (R11).

typedef __attribute__((ext_vector_type(8))) short short8_t;
typedef __attribute__((ext_vector_type(2))) unsigned uint2_t;
typedef __attribute__((ext_vector_type(8))) __bf16 bf16x8;
typedef __attribute__((ext_vector_type(4))) float f32x4;
typedef __attribute__((ext_vector_type(16))) float f32x16;

#define SEQLEN 2048
#define QSCALE 0.08838834764831845f   // HEAD_DIM^-0.5, folded into Q combine

__device__ __forceinline__ short f2b(float f) {
  if (!__builtin_isfinite(f)) f = 0.0f;   // diagnostic scrub (final stores only)
  union { float f; unsigned u; } v; v.f = f;
  unsigned r = (v.u + 0x7fffu + ((v.u >> 16) & 1u)) >> 16;  // RNE
  return (short)r;
}
__device__ __forceinline__ float sf(float f) {
  return __builtin_isfinite(f) ? f : 0.0f;
}
__device__ __forceinline__ short8_t cvt8(const float* p) {
  f32x4 a = *(const f32x4*)p;
  f32x4 b = *(const f32x4*)(p + 4);
  short8_t o;
  o[0] = f2b(a[0]); o[1] = f2b(a[1]); o[2] = f2b(a[2]); o[3] = f2b(a[3]);
  o[4] = f2b(b[0]); o[5] = f2b(b[1]); o[6] = f2b(b[2]); o[7] = f2b(b[3]);
  return o;
}
// pack two f32 -> (bf16 hi<<16 | bf16 lo); inputs finite by construction
__device__ __forceinline__ unsigned pkb(float lo, float hi) {
  union { float f; unsigned u; } a, b; a.f = lo; b.f = hi;
  unsigned ra = (a.u + 0x7fffu + ((a.u >> 16) & 1u)) >> 16;
  unsigned rb = (b.u + 0x7fffu + ((b.u >> 16) & 1u)) & 0xffff0000u;
  return rb | ra;
}

#define GLD16(gp, lp) __builtin_amdgcn_global_load_lds( \
    (const __attribute__((address_space(1))) void*)(gp), \
    (__attribute__((address_space(3))) void*)(lp), 16, 0, 0)

// ---------------------------------------------------------------------------
__global__ __launch_bounds__(256) void cvt_bf16(
    const float* __restrict__ in, short* __restrict__ out)
{
  size_t i = ((size_t)blockIdx.x * 256 + threadIdx.x) * 8;
  *(short8_t*)&out[i] = cvt8(in + i);
}

// ---------------------------------------------------------------------------
// GEMM (m97 structure): C[m][n] = sum_{k in [z*Kloop,(z+1)*Kloop)} A[m][k]W[n][k].
// A/W bf16 row-major (row stride lda); C f32 (C0 for z=0, C1 for z=1).
// ---------------------------------------------------------------------------
__global__ __launch_bounds__(256) void gemm_bf(
    const short* __restrict__ A, const short* __restrict__ W,
    float* __restrict__ C0, float* __restrict__ C1,
    int Kloop, int lda, int ldc)
{
  __shared__ short As[128 * 64];
  __shared__ short Ws[128 * 64];
  const int tid  = threadIdx.x;
  const int lane = tid & 63;
  const int wid  = tid >> 6;
  const int l15  = lane & 15;
  const int l4   = lane >> 4;

  const int nwg = (int)(gridDim.x * gridDim.y);
  int bid = (int)(blockIdx.y * gridDim.x + blockIdx.x);
  int swz = (bid & 7) * (nwg >> 3) + (bid >> 3);
  const int m0 = (swz / (int)gridDim.x) * 128;
  const int n0 = (swz % (int)gridDim.x) * 128;
  const int koff = (int)blockIdx.z * Kloop;
  float* C = blockIdx.z ? C1 : C0;

  const int wr = (wid >> 1) * 64;
  const int wc = (wid & 1) * 64;
  const int srow = tid >> 3;
  const int scol = (tid & 7) * 8;

  f32x4 acc[4][4] = {};

  const short* Ab = A + (size_t)(m0 + srow) * lda + koff + scol;
  const short* Wb = W + (size_t)(n0 + srow) * lda + koff + scol;

  for (int k0 = 0; k0 < Kloop; k0 += 64) {
#pragma unroll
    for (int i = 0; i < 4; ++i) {
      GLD16(Ab + (size_t)(i * 32) * lda + k0, &As[(i * 32 + wid * 8) * 64]);
      GLD16(Wb + (size_t)(i * 32) * lda + k0, &Ws[(i * 32 + wid * 8) * 64]);
    }
    __syncthreads();

#pragma unroll
    for (int kk = 0; kk < 2; ++kk) {
      bf16x8 af[4], wf[4];
#pragma unroll
      for (int m = 0; m < 4; ++m)
        af[m] = *(const bf16x8*)&As[(wr + m * 16 + l15) * 64 + kk * 32 + l4 * 8];
#pragma unroll
      for (int n = 0; n < 4; ++n)
        wf[n] = *(const bf16x8*)&Ws[(wc + n * 16 + l15) * 64 + kk * 32 + l4 * 8];
#pragma unroll
      for (int m = 0; m < 4; ++m)
#pragma unroll
        for (int n = 0; n < 4; ++n)
          acc[m][n] = __builtin_amdgcn_mfma_f32_16x16x32_bf16(af[m], wf[n], acc[m][n], 0, 0, 0);
    }
    __syncthreads();
  }

#pragma unroll
  for (int m = 0; m < 4; ++m) {
    int rbase = m0 + wr + m * 16 + l4 * 4;
#pragma unroll
    for (int n = 0; n < 4; ++n) {
      int cbase = n0 + wc + n * 16 + l15;
#pragma unroll
      for (int r = 0; r < 4; ++r)
        C[(size_t)(rbase + r) * ldc + cbase] = sf(acc[m][n][r]);
    }
  }
}

// ---------------------------------------------------------------------------
// RoPE on 8 summed values
// ---------------------------------------------------------------------------
__device__ __forceinline__ void rope8v(const float* x0, float* out,
                                       const float* fc, const float* fs, int t, int p0)
{
  f32x4 cv = *(const f32x4*)&fc[t * 64 + p0];
  f32x4 sv = *(const f32x4*)&fs[t * 64 + p0];
#pragma unroll
  for (int i = 0; i < 4; ++i) {
    float xr = x0[2 * i], xi = x0[2 * i + 1];
    out[2 * i]     = sf(xr * cv[i] - xi * sv[i]);
    out[2 * i + 1] = sf(xr * sv[i] + xi * cv[i]);
  }
}

// combine Q split-K partials + RoPE + scale -> q_bf  (2048 x 4096)
__global__ __launch_bounds__(256) void combine_rope_q(
    const float* __restrict__ p0, const float* __restrict__ p1,
    short* __restrict__ qb, const float* __restrict__ fc, const float* __restrict__ fs)
{
  size_t idx = ((size_t)blockIdx.x * 256 + threadIdx.x) * 8;
  int t   = (int)(idx >> 12);
  int col = (int)(idx & 4095);
  f32x4 a0 = *(const f32x4*)&p0[idx],     b0 = *(const f32x4*)&p0[idx + 4];
  f32x4 a1 = *(const f32x4*)&p1[idx],     b1 = *(const f32x4*)&p1[idx + 4];
  float s8[8] = {a0[0]+a1[0], a0[1]+a1[1], a0[2]+a1[2], a0[3]+a1[3],
                 b0[0]+b1[0], b0[1]+b1[1], b0[2]+b1[2], b0[3]+b1[3]};
  float o[8];
  rope8v(s8, o, fc, fs, t, (col & 127) >> 1);
  short8_t ob;
#pragma unroll
  for (int i = 0; i < 8; ++i) ob[i] = f2b(o[i] * QSCALE);
  *(short8_t*)&qb[idx] = ob;
}

// combine KV split-K partials; rows >= 2048 zero the cache tails.
// grid 4096 x 256 (8 f32/thread over [4096][2048] logical rows).
__global__ __launch_bounds__(256) void combine_rope_kv(
    const float* __restrict__ p0, const float* __restrict__ p1,
    float* __restrict__ ck, short* __restrict__ kb, float* __restrict__ cv,
    const float* __restrict__ fc, const float* __restrict__ fs)
{
  size_t idx = ((size_t)blockIdx.x * 256 + threadIdx.x) * 8;
  int t   = (int)(idx >> 11);
  int col = (int)(idx & 2047);
  if (t >= 2048) {   // cache tail: zeros (reference leaves cache rows 2048+ at 0)
    size_t di = (size_t)t * 1024 + (col & 1023);
    float* dst = (col < 1024) ? ck : cv;
    *(f32x4*)&dst[di]     = f32x4{0.f, 0.f, 0.f, 0.f};
    *(f32x4*)&dst[di + 4] = f32x4{0.f, 0.f, 0.f, 0.f};
    return;
  }
  f32x4 a0 = *(const f32x4*)&p0[idx],     b0 = *(const f32x4*)&p0[idx + 4];
  f32x4 a1 = *(const f32x4*)&p1[idx],     b1 = *(const f32x4*)&p1[idx + 4];
  float s8[8] = {a0[0]+a1[0], a0[1]+a1[1], a0[2]+a1[2], a0[3]+a1[3],
                 b0[0]+b1[0], b0[1]+b1[1], b0[2]+b1[2], b0[3]+b1[3]};
  if (col < 1024) {
    float o[8];
    rope8v(s8, o, fc, fs, t, (col & 127) >> 1);
    size_t di = (size_t)t * 1024 + col;
    *(f32x4*)&ck[di]     = f32x4{o[0], o[1], o[2], o[3]};
    *(f32x4*)&ck[di + 4] = f32x4{o[4], o[5], o[6], o[7]};
    short8_t ob;
#pragma unroll
    for (int i = 0; i < 8; ++i) ob[i] = f2b(o[i]);
    *(short8_t*)&kb[di] = ob;
  } else {
    size_t di = (size_t)t * 1024 + (col - 1024);
    *(f32x4*)&cv[di]     = f32x4{sf(s8[0]), sf(s8[1]), sf(s8[2]), sf(s8[3])};
    *(f32x4*)&cv[di + 4] = f32x4{sf(s8[4]), sf(s8[5]), sf(s8[6]), sf(s8[7])};
  }
}

// cache_v f32 [2048][8*128] -> Vt bf16 [8][128][2048]
__global__ __launch_bounds__(256) void transpose_v(
    const float* __restrict__ cv, short* __restrict__ Vt)
{
  __shared__ short tile[64][72];
  const int t0 = blockIdx.x * 64;
  const int d0 = blockIdx.y * 64;
  const int h  = blockIdx.z;
  const int tid = threadIdx.x;
  const int r = tid >> 3;
  const int c = (tid & 7) * 8;
#pragma unroll
  for (int it = 0; it < 2; ++it) {
    short8_t v = cvt8(&cv[(size_t)(t0 + it * 32 + r) * 1024 + h * 128 + d0 + c]);
    *(short8_t*)&tile[it * 32 + r][c] = v;
  }
  __syncthreads();
#pragma unroll
  for (int it = 0; it < 2; ++it) {
    int dr = it * 32 + r;
    short8_t v;
#pragma unroll
    for (int i = 0; i < 8; ++i) v[i] = tile[c + i][dr];
    *(short8_t*)&Vt[(size_t)(h * 128 + d0 + dr) * SEQLEN + t0 + c] = v;
  }
}

// ---------------------------------------------------------------------------
// Causal flash attention (R15-proven attn_fwd7, unchanged).
// Grid 512 x 256 thr: bid&7 = kvh (XCD pin), qt = 63-(bid>>3) heavy-first.
// 4 waves = 4 heads share staged K [64][128] / V [128][64] (XOR swizzle).
// Lane state: q = lane&31, S^T keys = crow(r,hi) = (r&3)+8*(r>>2)+4*hi.
// ---------------------------------------------------------------------------
__global__ __launch_bounds__(256) void attn_fwd7(
    const short* __restrict__ Q,    // [2048][4096] bf16, pre-scaled
    const short* __restrict__ Kc,   // [2048][1024] bf16
    const short* __restrict__ Vt,   // [8][128][2048] bf16
    short* __restrict__ O)          // [2048][4096] bf16
{
  const int bid = (int)blockIdx.x;
  const int kvh = bid & 7;
  const int qt  = 63 - (bid >> 3);
  const int tid = (int)threadIdx.x;
  const int wid = tid >> 6;
  const int h   = kvh * 4 + wid;
  const int lane = tid & 63;
  const int l31 = lane & 31;
  const int hi  = lane >> 5;

  __shared__ short Ks[64 * 128];
  __shared__ short Vs[128 * 64];
  __shared__ short P[4][32][72];
  __shared__ float exch[4][32];

  const int q0 = qt * 32;
  const int qg = q0 + l31;
  const int kend = q0 + 32;

  bf16x8 qf[8];
  {
    const short* qp = Q + (size_t)qg * 4096 + h * 128 + hi * 8;
#pragma unroll
    for (int ks = 0; ks < 8; ++ks) qf[ks] = *(const bf16x8*)(qp + ks * 16);
  }

  f32x16 o0 = {}, o1 = {}, o2 = {}, o3 = {};
  float m = -1e30f, l = 0.f;

  const int krow_base = wid * 16;
  const int vrow_base = wid * 32;
  const int xk = l31 & 15;
  const int xv = l31 & 7;

  for (int kt = 0; kt < kend; kt += 64) {
#pragma unroll
    for (int it = 0; it < 4; ++it) {
      int krow = krow_base + it * 4 + (lane >> 4);
      int kch  = (lane & 15) ^ (krow & 15);
      GLD16(Kc + (size_t)(kt + krow) * 1024 + kvh * 128 + kch * 8,
            &Ks[wid * 2048 + it * 512]);
      int vrow = vrow_base + it * 8 + (lane >> 3);
      int vch  = (lane & 7) ^ (vrow & 7);
      GLD16(Vt + (size_t)(kvh * 128 + vrow) * SEQLEN + kt + vch * 8,
            &Vs[wid * 2048 + it * 512]);
    }
    __syncthreads();

    f32x16 s0 = {}, s1 = {};
    {
      __builtin_amdgcn_s_setprio(1);
#pragma unroll
      for (int ks = 0; ks < 8; ++ks) {
        int ch = (ks * 2 + hi) ^ xk;
        bf16x8 k0 = *(const bf16x8*)&Ks[l31 * 128 + ch * 8];
        bf16x8 k1 = *(const bf16x8*)&Ks[(32 + l31) * 128 + ch * 8];
        s0 = __builtin_amdgcn_mfma_f32_32x32x16_bf16(k0, qf[ks], s0, 0, 0, 0);
        s1 = __builtin_amdgcn_mfma_f32_32x32x16_bf16(k1, qf[ks], s1, 0, 0, 0);
      }
      __builtin_amdgcn_s_setprio(0);
    }

    if (kt + 63 > q0) {
#pragma unroll
      for (int r = 0; r < 16; ++r) {
        int crow = (r & 3) + 8 * (r >> 2) + 4 * hi;
        if (kt + crow > qg)      s0[r] = -1e30f;
        if (kt + 32 + crow > qg) s1[r] = -1e30f;
      }
    }
    {
      float t[8];
#pragma unroll
      for (int r = 0; r < 8; ++r)
        t[r] = fmaxf(fmaxf(s0[r], s0[r + 8]), fmaxf(s1[r], s1[r + 8]));
      float pmax = fmaxf(fmaxf(fmaxf(t[0], t[1]), fmaxf(t[2], t[3])),
                         fmaxf(fmaxf(t[4], t[5]), fmaxf(t[6], t[7])));
      pmax = fmaxf(pmax, __shfl_xor(pmax, 32, 64));
      if (!__all(pmax <= m + 8.f)) {
        float mnew = fmaxf(m, pmax);
        float resc = __expf(m - mnew);
        m = mnew; l *= resc;
        if (lane < 32) exch[wid][l31] = resc;
#pragma unroll
        for (int r = 0; r < 16; ++r) {
          float rs = exch[wid][(r & 3) + 8 * (r >> 2) + 4 * hi];
          o0[r] *= rs; o1[r] *= rs; o2[r] *= rs; o3[r] *= rs;
        }
      }
      float psum = 0.f;
#pragma unroll
      for (int r = 0; r < 16; ++r) { s0[r] = __expf(s0[r] - m); psum += s0[r]; }
#pragma unroll
      for (int r = 0; r < 16; ++r) { s1[r] = __expf(s1[r] - m); psum += s1[r]; }
      l += psum + __shfl_xor(psum, 32, 64);
#pragma unroll
      for (int t4 = 0; t4 < 4; ++t4) {
        int c = 8 * t4 + 4 * hi;
        *(uint2_t*)&P[wid][l31][c]      = uint2_t{pkb(s0[4*t4], s0[4*t4+1]), pkb(s0[4*t4+2], s0[4*t4+3])};
        *(uint2_t*)&P[wid][l31][32 + c] = uint2_t{pkb(s1[4*t4], s1[4*t4+1]), pkb(s1[4*t4+2], s1[4*t4+3])};
      }
    }

#pragma unroll
    for (int g = 0; g < 4; ++g) {
      int ch = (g * 2 + hi) ^ xv;
      bf16x8 vf0 = *(const bf16x8*)&Vs[(l31)      * 64 + ch * 8];
      bf16x8 vf1 = *(const bf16x8*)&Vs[(32 + l31) * 64 + ch * 8];
      bf16x8 vf2 = *(const bf16x8*)&Vs[(64 + l31) * 64 + ch * 8];
      bf16x8 vf3 = *(const bf16x8*)&Vs[(96 + l31) * 64 + ch * 8];
      bf16x8 pf  = *(const bf16x8*)&P[wid][l31][g * 16 + hi * 8];
      __builtin_amdgcn_s_setprio(1);
      o0 = __builtin_amdgcn_mfma_f32_32x32x16_bf16(pf, vf0, o0, 0, 0, 0);
      o1 = __builtin_amdgcn_mfma_f32_32x32x16_bf16(pf, vf1, o1, 0, 0, 0);
      o2 = __builtin_amdgcn_mfma_f32_32x32x16_bf16(pf, vf2, o2, 0, 0, 0);
      o3 = __builtin_amdgcn_mfma_f32_32x32x16_bf16(pf, vf3, o3, 0, 0, 0);
      __builtin_amdgcn_s_setprio(0);
    }
    __syncthreads();
  }

  if (lane < 32) exch[wid][l31] = 1.f / l;
#pragma unroll
  for (int r = 0; r < 16; ++r) {
    int crow = (r & 3) + 8 * (r >> 2) + 4 * hi;
    float inv = exch[wid][crow];
    short* ob = O + (size_t)(q0 + crow) * 4096 + h * 128 + l31;
    ob[0]  = f2b(o0[r] * inv);
    ob[32] = f2b(o1[r] * inv);
    ob[64] = f2b(o2[r] * inv);
    ob[96] = f2b(o3[r] * inv);
  }
}

// ---------------------------------------------------------------------------
extern "C" void kernel_launch(void* const* d_in, const int* in_sizes, int n_in,
                              void* d_out, int out_size, void* d_ws, size_t ws_size,
                              hipStream_t stream) {
  const float* x  = (const float*)d_in[0];
  const float* wq = (const float*)d_in[1];
  const float* wk = (const float*)d_in[2];
  const float* wv = (const float*)d_in[3];
  const float* wo = (const float*)d_in[4];
  const float* fc = (const float*)d_in[5];
  const float* fs = (const float*)d_in[6];

  float* out = (float*)d_out;
  float* out_main = out;                               // [2048][4096] f32
  float* cache_k  = out + (size_t)2048 * 4096;         // [4096][8][128] f32
  float* cache_v  = cache_k + (size_t)4096 * 8 * 128;

  // ws 54.5MB: slotA 33.5 | slotB 16.8 | Vt 4.2
  short* slotA = (short*)d_ws;                         // wq_bf / q_bf+k_bf / wo_bf
  short* slotB = (short*)((char*)d_ws + 33554432);     // x_bf / attn_out
  short* Vt    = (short*)((char*)d_ws + 33554432 + 16777216);
  short* x_bf  = slotB;
  short* attn_out = slotB;
  short* q_bf  = slotA;                                // 16.8MB
  short* wkv_bf = slotA + (size_t)2048 * 4096;         // wk_bf+wv_bf (16.8MB)
  short* k_bf  = slotA + (size_t)2048 * 4096;          // overwrites wkv_bf post-GEMM

  // split-K partial buffers (f32) in dead d_out regions:
  float* pQ0 = out_main;                               // 33.5MB
  float* pQ1 = cache_k;                                // 33.5MB (cache region, pre-write)
  float* pKV0 = out_main;                              // 16.8MB (Q partials dead)
  float* pKV1 = out_main + (size_t)2048 * 2048;        // 16.8MB

  // 1) converts + Q projection (split-K x2) + fused combine+rope -> q_bf
  cvt_bf16<<<4096, 256, 0, stream>>>(x, x_bf);
  cvt_bf16<<<8192, 256, 0, stream>>>(wq, slotA);
  gemm_bf<<<dim3(32, 16, 2), 256, 0, stream>>>(x_bf, slotA, pQ0, pQ1, 2048, 4096, 4096);
  combine_rope_q<<<4096, 256, 0, stream>>>(pQ0, pQ1, q_bf, fc, fs);

  // 2) KV projection (split-K x2) + fused combine+rope (also zeroes cache tails)
  cvt_bf16<<<2048, 256, 0, stream>>>(wk, wkv_bf);
  cvt_bf16<<<2048, 256, 0, stream>>>(wv, wkv_bf + (size_t)1024 * 4096);
  gemm_bf<<<dim3(16, 16, 2), 256, 0, stream>>>(x_bf, wkv_bf, pKV0, pKV1, 2048, 4096, 2048);
  combine_rope_kv<<<4096, 256, 0, stream>>>(pKV0, pKV1, cache_k, k_bf, cache_v, fc, fs);
  transpose_v<<<dim3(32, 2, 8), 256, 0, stream>>>(cache_v, Vt);

  // 3) attention: 512 single-q-tile blocks, heavy-first, XCD-pinned
  attn_fwd7<<<512, 256, 0, stream>>>(q_bf, k_bf, Vt, attn_out);

  // 4) output projection (full K, single pass; atomics regressed in R17)
  cvt_bf16<<<8192, 256, 0, stream>>>(wo, slotA);
  gemm_bf<<<dim3(32, 16, 1), 256, 0, stream>>>(attn_out, slotA, out_main, nullptr, 4096, 4096, 4096);
}